// Round 5
// baseline (214.643 us; speedup 1.0000x reference)
//
#include <hip/hip_runtime.h>

// YOLO-v1 loss, S=14, B=2, C=20, NCH=30, Nb=4096.
// R6: R3/R4/R5 all flat at ~73us / 1.34 TB/s across 3x occupancy and load-shape
// changes -> bottleneck is TA address divergence: 120B-stride per-lane loads
// touch ~60 cache lines per wave-instruction. Fix: coalesced global_load_lds
// staging (16 lines/instr) like R2, but chunked + double-buffered so the HBM
// stream never drains idle (R2 staged 60KB then drained to zero, 83us).
// Chunk=128 cells (30.7KB both tensors), dbuf=61.5KB LDS -> 2 blocks/CU,
// ~61KB HBM-in-flight/CU. Stage(next) issued BEFORE compute(cur), so the
// compiler's vmcnt(0)-before-barrier drain overlaps compute + the other block.

#define NB 4096
#define NCELL (NB * 14 * 14)               // 802816
#define NCH 30
#define CHUNK_CELLS 128
#define CHUNKS_PER_BLOCK 8
#define CELLS_PER_BLOCK (CHUNK_CELLS * CHUNKS_PER_BLOCK)   // 1024
#define NBLOCKS (NCELL / CELLS_PER_BLOCK)  // 784
#define CHUNK_FLOATS (CHUNK_CELLS * NCH)   // 3840 floats = 15360 B
#define CHUNK_F4 (CHUNK_FLOATS / 4)        // 960 float4 per tensor per chunk

#define GLOBAL_AS __attribute__((address_space(1)))
#define LDS_AS    __attribute__((address_space(3)))

__device__ __forceinline__ void async_copy16(const float* g, float* l) {
    __builtin_amdgcn_global_load_lds((const GLOBAL_AS void*)g, (LDS_AS void*)l,
                                     16, 0, 0);
}

// Stage one chunk (both tensors) into LDS: 960 float4 per tensor, 256 lanes.
// Rounds 0..2 full, round 3 has 192 active lanes (960 = 3*256 + 192).
__device__ __forceinline__ void stage_chunk(const float* __restrict__ pred,
                                            const float* __restrict__ target,
                                            float* pbuf, float* tbuf,
                                            size_t cellbase, int tid)
{
    const float* gp = pred + cellbase * NCH;
    const float* gt = target + cellbase * NCH;
#pragma unroll
    for (int r = 0; r < 4; ++r) {
        int idx = r * 256 + tid;
        if (idx < CHUNK_F4) {
            async_copy16(gp + (size_t)idx * 4, pbuf + idx * 4);
            async_copy16(gt + (size_t)idx * 4, tbuf + idx * 4);
        }
    }
}

// Per-cell YOLO loss computed from LDS (stride-30 rows: gcd(30,32)=2 -> 2-way
// bank aliasing, which is free on CDNA4).
__device__ __forceinline__ float cell_loss_lds(const float* __restrict__ pl,
                                               const float* __restrict__ tl)
{
    const float2* p2 = (const float2*)pl;   // tid*120B: 8B-aligned
    const float2* t2 = (const float2*)tl;

    float p[10], t[10];
#pragma unroll
    for (int i = 0; i < 5; ++i) {
        float2 a = p2[i]; p[2 * i] = a.x; p[2 * i + 1] = a.y;
        float2 b = t2[i]; t[2 * i] = b.x; t[2 * i + 1] = b.y;
    }

    const float t4 = t[4];
    const bool obj = (t4 > 0.0f);

    float dn0 = p[4] - t[4];
    float dn1 = p[9] - t[9];
    float noobj_l = (t4 == 0.0f) ? (dn0 * dn0 + dn1 * dn1) : 0.0f;

    const float invS = 1.0f / 14.0f;
    float tcx = t[0] * invS, tcy = t[1] * invS;
    float tx1 = tcx - 0.5f * t[2], ty1 = tcy - 0.5f * t[3];
    float tx2 = tcx + 0.5f * t[2], ty2 = tcy + 0.5f * t[3];
    float area_t = (tx2 - tx1) * (ty2 - ty1);

    float iou[2];
#pragma unroll
    for (int b = 0; b < 2; ++b) {
        const float* pb = p + 5 * b;
        float cx = pb[0] * invS, cy = pb[1] * invS;
        float x1 = cx - 0.5f * pb[2], y1 = cy - 0.5f * pb[3];
        float x2 = cx + 0.5f * pb[2], y2 = cy + 0.5f * pb[3];
        float lx = fmaxf(x1, tx1), ly = fmaxf(y1, ty1);
        float rx = fminf(x2, tx2), ry = fminf(y2, ty2);
        float wx = fmaxf(rx - lx, 0.0f), wy = fmaxf(ry - ly, 0.0f);
        float inter = wx * wy;
        float area_p = (x2 - x1) * (y2 - y1);
        iou[b] = inter / (area_p + area_t - inter);
    }

    // jnp.argmax picks first max -> box 1 only on strict >
    const bool r = (iou[1] > iou[0]);
    float max_iou = fmaxf(iou[0], iou[1]);

    float pr0 = r ? p[5] : p[0], tr0 = r ? t[5] : t[0];
    float pr1 = r ? p[6] : p[1], tr1 = r ? t[6] : t[1];
    float pr2 = r ? p[7] : p[2], tr2 = r ? t[7] : t[2];
    float pr3 = r ? p[8] : p[3], tr3 = r ? t[8] : t[3];
    float pr4 = r ? p[9] : p[4];

    float lcls = 0.0f;
#pragma unroll
    for (int i = 5; i < 15; ++i) {
        float2 a = p2[i];
        float2 b = t2[i];
        float d0 = a.x - b.x, d1 = a.y - b.y;
        lcls += d0 * d0 + d1 * d1;
    }

    float obj_l = 0.0f;
    if (obj) {
        float dx = pr0 - tr0, dy = pr1 - tr1;
        float lxy = dx * dx + dy * dy;
        float dw = sqrtf(pr2) - sqrtf(tr2);
        float dh = sqrtf(pr3) - sqrtf(tr3);
        float lwh = dw * dw + dh * dh;
        float dob = pr4 - max_iou;
        float lob = dob * dob;
        obj_l = 5.0f * (lxy + lwh) + lob + lcls;
    }
    return obj_l + 0.5f * noobj_l;
}

__global__ __launch_bounds__(256) void yolo_loss_partial(
    const float* __restrict__ pred, const float* __restrict__ target,
    float* __restrict__ partial)
{
    __shared__ __align__(16) float buf[2][2][CHUNK_FLOATS];   // 61,440 B
    __shared__ float red[4];

    const int tid = threadIdx.x;
    const size_t blockcell = (size_t)blockIdx.x * CELLS_PER_BLOCK;

    // prologue: stage chunk 0 into buf[0]
    stage_chunk(pred, target, buf[0][0], buf[0][1], blockcell, tid);
    __syncthreads();   // vmcnt(0) drain: chunk 0 landed

    float acc = 0.0f;
    for (int c = 0; c < CHUNKS_PER_BLOCK; ++c) {
        const int cur = c & 1;
        // issue next chunk's loads FIRST (stream continues during compute+wait)
        if (c + 1 < CHUNKS_PER_BLOCK)
            stage_chunk(pred, target, buf[cur ^ 1][0], buf[cur ^ 1][1],
                        blockcell + (size_t)(c + 1) * CHUNK_CELLS, tid);
        // compute current chunk from LDS (waves 0-1 only; 2-3 stage-only)
        if (tid < CHUNK_CELLS)
            acc += cell_loss_lds(&buf[cur][0][tid * NCH],
                                 &buf[cur][1][tid * NCH]);
        // drains chunk c+1 loads; also guards buf[cur] reuse at c+2's stage
        __syncthreads();
    }

    // wave (64-lane) shuffle reduce, then cross-wave via LDS
    float v = acc;
#pragma unroll
    for (int off = 32; off > 0; off >>= 1)
        v += __shfl_down(v, off, 64);

    const int lane = threadIdx.x & 63;
    const int wid = threadIdx.x >> 6;
    if (lane == 0) red[wid] = v;
    __syncthreads();
    if (threadIdx.x == 0)
        partial[blockIdx.x] = red[0] + red[1] + red[2] + red[3];
}

__global__ __launch_bounds__(256) void yolo_loss_finalize(
    const float* __restrict__ partial, float* __restrict__ out)
{
    double s = 0.0;
    for (int i = threadIdx.x; i < NBLOCKS; i += 256)
        s += (double)partial[i];

    __shared__ double sh[256];
    sh[threadIdx.x] = s;
    __syncthreads();
#pragma unroll
    for (int step = 128; step > 0; step >>= 1) {
        if (threadIdx.x < step) sh[threadIdx.x] += sh[threadIdx.x + step];
        __syncthreads();
    }
    if (threadIdx.x == 0)
        out[0] = (float)(sh[0] / (double)NB);
}

extern "C" void kernel_launch(void* const* d_in, const int* in_sizes, int n_in,
                              void* d_out, int out_size, void* d_ws, size_t ws_size,
                              hipStream_t stream) {
    const float* pred = (const float*)d_in[0];
    const float* target = (const float*)d_in[1];
    float* out = (float*)d_out;
    float* partial = (float*)d_ws;   // NBLOCKS floats = 3.1 KB scratch

    yolo_loss_partial<<<NBLOCKS, 256, 0, stream>>>(pred, target, partial);
    yolo_loss_finalize<<<1, 256, 0, stream>>>(partial, out);
}

// Round 7
// 211.394 us; speedup vs baseline: 1.0154x; 1.0154x over previous
//
#include <hip/hip_runtime.h>

// YOLO-v1 loss, S=14, B=2, C=20, NCH=30, Nb=4096.
// R8: R7's NaN had two candidate causes (12B global_load_lds lane-stride
// unverified; missing sched_barrier after trailing s_barrier). R8 removes
// both AND all cross-wave coupling: 64-thread blocks, each wave stages its
// own 128-cell region = 15360 B/tensor = exactly 15 x (64 lanes x 16B) --
// 16B-only staging. Counted waits, never a barrier: issue all 30 loads
// interleaved (P0,T0,..,P14,T14), vmcnt(14) -> compute cells 0..63,
// vmcnt(0) -> compute cells 64..127. 30.7 KB LDS -> 5 blocks(waves)/CU,
// each wave up to 30 KB in flight, independent drain -> HBM never idles.

#define NB 4096
#define NCELL (NB * 14 * 14)            // 802816
#define NCH 30
#define WAVE_CELLS 128
#define NBLOCKS (NCELL / WAVE_CELLS)    // 6272
#define SEG 1024                        // bytes per staging instr (64 x 16B)

#define GLOBAL_AS __attribute__((address_space(1)))
#define LDS_AS    __attribute__((address_space(3)))

__device__ __forceinline__ void async16(const char* g, char* l) {
    __builtin_amdgcn_global_load_lds((const GLOBAL_AS void*)g, (LDS_AS void*)l,
                                     16, 0, 0);
}

// Per-cell YOLO loss from LDS (stride-30-float rows; 4-way bank aliasing on
// float2 reads, ~1.6x LDS cost -- LDS is not the critical path).
__device__ __forceinline__ float cell_loss_lds(const float* __restrict__ pl,
                                               const float* __restrict__ tl)
{
    const float2* p2 = (const float2*)pl;   // 120B rows: 8B-aligned
    const float2* t2 = (const float2*)tl;

    float p[10], t[10];
#pragma unroll
    for (int i = 0; i < 5; ++i) {
        float2 a = p2[i]; p[2 * i] = a.x; p[2 * i + 1] = a.y;
        float2 b = t2[i]; t[2 * i] = b.x; t[2 * i + 1] = b.y;
    }

    const float t4 = t[4];
    const bool obj = (t4 > 0.0f);

    float dn0 = p[4] - t[4];
    float dn1 = p[9] - t[9];
    float noobj_l = (t4 == 0.0f) ? (dn0 * dn0 + dn1 * dn1) : 0.0f;

    const float invS = 1.0f / 14.0f;
    float tcx = t[0] * invS, tcy = t[1] * invS;
    float tx1 = tcx - 0.5f * t[2], ty1 = tcy - 0.5f * t[3];
    float tx2 = tcx + 0.5f * t[2], ty2 = tcy + 0.5f * t[3];
    float area_t = (tx2 - tx1) * (ty2 - ty1);

    float iou[2];
#pragma unroll
    for (int b = 0; b < 2; ++b) {
        const float* pb = p + 5 * b;
        float cx = pb[0] * invS, cy = pb[1] * invS;
        float x1 = cx - 0.5f * pb[2], y1 = cy - 0.5f * pb[3];
        float x2 = cx + 0.5f * pb[2], y2 = cy + 0.5f * pb[3];
        float lx = fmaxf(x1, tx1), ly = fmaxf(y1, ty1);
        float rx = fminf(x2, tx2), ry = fminf(y2, ty2);
        float wx = fmaxf(rx - lx, 0.0f), wy = fmaxf(ry - ly, 0.0f);
        float inter = wx * wy;
        float area_p = (x2 - x1) * (y2 - y1);
        iou[b] = inter / (area_p + area_t - inter);
    }

    // jnp.argmax picks first max -> box 1 only on strict >
    const bool r = (iou[1] > iou[0]);
    float max_iou = fmaxf(iou[0], iou[1]);

    float pr0 = r ? p[5] : p[0], tr0 = r ? t[5] : t[0];
    float pr1 = r ? p[6] : p[1], tr1 = r ? t[6] : t[1];
    float pr2 = r ? p[7] : p[2], tr2 = r ? t[7] : t[2];
    float pr3 = r ? p[8] : p[3], tr3 = r ? t[8] : t[3];
    float pr4 = r ? p[9] : p[4];

    float lcls = 0.0f;
#pragma unroll
    for (int i = 5; i < 15; ++i) {
        float2 a = p2[i];
        float2 b = t2[i];
        float d0 = a.x - b.x, d1 = a.y - b.y;
        lcls += d0 * d0 + d1 * d1;
    }

    float obj_l = 0.0f;
    if (obj) {
        float dx = pr0 - tr0, dy = pr1 - tr1;
        float lxy = dx * dx + dy * dy;
        float dw = sqrtf(pr2) - sqrtf(tr2);
        float dh = sqrtf(pr3) - sqrtf(tr3);
        float lwh = dw * dw + dh * dh;
        float dob = pr4 - max_iou;
        float lob = dob * dob;
        obj_l = 5.0f * (lxy + lwh) + lob + lcls;
    }
    return obj_l + 0.5f * noobj_l;
}

__global__ __launch_bounds__(64) void yolo_loss_partial(
    const float* __restrict__ pred, const float* __restrict__ target,
    float* __restrict__ partial)
{
    __shared__ __align__(16) float pbuf[WAVE_CELLS * NCH];   // 15360 B
    __shared__ __align__(16) float tbuf[WAVE_CELLS * NCH];   // 15360 B

    const int lane = threadIdx.x;                            // block == wave
    const size_t base = (size_t)blockIdx.x * WAVE_CELLS * NCH;   // floats
    const char* gp = (const char*)(pred + base);
    const char* gt = (const char*)(target + base);
    char* lp = (char*)pbuf;
    char* lt = (char*)tbuf;
    const int lo = lane * 16;

    // Issue all 30 staging loads, interleaved P_r,T_r. Each covers 1024 B;
    // LDS dest is wave-uniform base (lane0: lo=0) + lane*16 -> linear.
#pragma unroll
    for (int r = 0; r < 15; ++r) {
        async16(gp + r * SEG + lo, lp + r * SEG + lo);
        async16(gt + r * SEG + lo, lt + r * SEG + lo);
    }

    // Phase A: cells 0..63 need bytes [0,7680) of each tensor, covered by
    // P0..P7 + T0..T7 = the 16 oldest issues -> 14 may remain in flight.
    asm volatile("s_waitcnt vmcnt(14)" ::: "memory");
    __builtin_amdgcn_sched_barrier(0);
    float acc = cell_loss_lds(pbuf + lane * NCH, tbuf + lane * NCH);

    // Phase B: cells 64..127 need everything.
    asm volatile("s_waitcnt vmcnt(0)" ::: "memory");
    __builtin_amdgcn_sched_barrier(0);
    acc += cell_loss_lds(pbuf + (64 + lane) * NCH, tbuf + (64 + lane) * NCH);

    // single-wave shuffle reduce; no barriers anywhere in this kernel
    float v = acc;
#pragma unroll
    for (int off = 32; off > 0; off >>= 1)
        v += __shfl_down(v, off, 64);
    if (lane == 0)
        partial[blockIdx.x] = v;
}

__global__ __launch_bounds__(256) void yolo_loss_finalize(
    const float* __restrict__ partial, float* __restrict__ out)
{
    double s = 0.0;
    for (int i = threadIdx.x; i < NBLOCKS; i += 256)
        s += (double)partial[i];

    __shared__ double sh[256];
    sh[threadIdx.x] = s;
    __syncthreads();
#pragma unroll
    for (int step = 128; step > 0; step >>= 1) {
        if (threadIdx.x < step) sh[threadIdx.x] += sh[threadIdx.x + step];
        __syncthreads();
    }
    if (threadIdx.x == 0)
        out[0] = (float)(sh[0] / (double)NB);
}

extern "C" void kernel_launch(void* const* d_in, const int* in_sizes, int n_in,
                              void* d_out, int out_size, void* d_ws, size_t ws_size,
                              hipStream_t stream) {
    const float* pred = (const float*)d_in[0];
    const float* target = (const float*)d_in[1];
    float* out = (float*)d_out;
    float* partial = (float*)d_ws;   // NBLOCKS floats = 25 KB scratch

    yolo_loss_partial<<<NBLOCKS, 64, 0, stream>>>(pred, target, partial);
    yolo_loss_finalize<<<1, 256, 0, stream>>>(partial, out);
}